// Round 3
// baseline (302.569 us; speedup 1.0000x reference)
//
#include <hip/hip_runtime.h>
#include <math.h>

// Problem constants (fixed by reference)
#define N_V  2048   // vertices
#define N_E  8192   // edges

// float4 elements per one-hot matrix [N_V, N_E] -> N_V * N_E/4
#define NE4            (N_V * (N_E / 4))     // 4,194,304
#define SCAN_ITER      8
#define SCAN_BPM       (NE4 / (256 * SCAN_ITER))   // 2048 blocks per matrix

static __device__ __forceinline__ float leaky(float x) {
    return x >= 0.f ? x : 0.01f * x;
}

// ---- K1: scan one-hot vew1/vew2 -> src/dst indices ----
// Latency fix vs r1: compile-time trip count, 8 independent float4 loads
// batched into registers before any testing -> 8 KB in flight per wave.
__global__ __launch_bounds__(256) void k_scan(const float4* __restrict__ vew1,
                                              const float4* __restrict__ vew2,
                                              int* __restrict__ src,
                                              int* __restrict__ dst)
{
    const int  bm     = blockIdx.x & (SCAN_BPM - 1);
    const bool second = blockIdx.x >= SCAN_BPM;
    const float4* __restrict__ p = second ? vew2 : vew1;
    int* __restrict__ arr        = second ? dst : src;

    const int base = bm * (256 * SCAN_ITER) + threadIdx.x;

    float4 v[SCAN_ITER];
#pragma unroll
    for (int k = 0; k < SCAN_ITER; ++k) v[k] = p[base + k * 256];

#pragma unroll
    for (int k = 0; k < SCAN_ITER; ++k) {
        const float4 q = v[k];
        if (q.x != 0.f || q.y != 0.f || q.z != 0.f || q.w != 0.f) {
            const int i  = base + k * 256;
            const int n  = i >> 11;            // row (vertex): E/4 = 2048 = 2^11
            const int e4 = (i & 2047) << 2;    // edge index base
            if (q.x != 0.f) arr[e4 + 0] = n;
            if (q.y != 0.f) arr[e4 + 1] = n;
            if (q.z != 0.f) arr[e4 + 2] = n;
            if (q.w != 0.f) arr[e4 + 3] = n;
        }
    }
}

// ---- K2: indeg[n] = #(src==n) + #(dst==n)  over e in [0, N_E) ----
// r2 BUG FIX: grid must cover exactly N_E edges (src/dst are N_E long each);
// the 2*N_E launch read past the arrays -> wild atomics -> abort.
__global__ __launch_bounds__(256) void k_indeg(const int* __restrict__ src,
                                               const int* __restrict__ dst,
                                               int* __restrict__ indeg)
{
    const int e = blockIdx.x * 256 + threadIdx.x;   // grid 32 -> 8192
    atomicAdd(&indeg[src[e]], 1);
    atomicAdd(&indeg[dst[e]], 1);
}

// ---- K3: per-vertex GEMMs, 8 rows/block, 768 blocks (3/CU). ----
// mat 0: X  = leaky(hv @ attend_w + attend_b); also mv_out = elu(X)
// mat 1: Au = hv @ Wu - Zpq            (Wu = link_w rows [0,256))
// mat 2: Av = hv @ Wv + Zpq + link_b   (Wv = link_w rows [262,518))
// Zpq[n][j] = p[n]·link_w[256..258][j] + q[n]·link_w[259..261][j]
__global__ __launch_bounds__(256) void k_gemm(const float* __restrict__ hv,
                                              const float* __restrict__ attend_w,
                                              const float* __restrict__ attend_b,
                                              const float* __restrict__ link_w,
                                              const float* __restrict__ link_b,
                                              const float* __restrict__ p_ftr,
                                              const float* __restrict__ q_ftr,
                                              float* __restrict__ X,
                                              float* __restrict__ Au,
                                              float* __restrict__ Av,
                                              float* __restrict__ mv_out)
{
    const int mat  = blockIdx.y;           // 0:X 1:Au 2:Av
    const int row0 = blockIdx.x * 8;
    const int j    = threadIdx.x;          // output column 0..255

    const float* __restrict__ B =
        (mat == 0) ? attend_w : (mat == 1 ? link_w : link_w + 262 * 256);

    float acc[8];
#pragma unroll
    for (int r = 0; r < 8; ++r) acc[r] = 0.f;

    const float* __restrict__ A = hv + row0 * 256;   // wave-uniform rows

#pragma unroll 4
    for (int k = 0; k < 256; k += 8) {
        float b[8];
#pragma unroll
        for (int t = 0; t < 8; ++t) b[t] = B[(k + t) * 256 + j];
#pragma unroll
        for (int r = 0; r < 8; ++r) {
#pragma unroll
            for (int t = 0; t < 8; ++t)
                acc[r] = fmaf(A[r * 256 + k + t], b[t], acc[r]);
        }
    }

    if (mat == 0) {
        const float bias = attend_b[j];
#pragma unroll
        for (int r = 0; r < 8; ++r) {
            float x = leaky(acc[r] + bias);
            X[(row0 + r) * 256 + j]      = x;
            mv_out[(row0 + r) * 256 + j] = (x > 0.f) ? x : expm1f(x);
        }
    } else {
        const float wp0 = link_w[(256 + 0) * 256 + j];
        const float wp1 = link_w[(256 + 1) * 256 + j];
        const float wp2 = link_w[(256 + 2) * 256 + j];
        const float wq0 = link_w[(259 + 0) * 256 + j];
        const float wq1 = link_w[(259 + 1) * 256 + j];
        const float wq2 = link_w[(259 + 2) * 256 + j];
        const float lb  = (mat == 2) ? link_b[j] : 0.f;
#pragma unroll
        for (int r = 0; r < 8; ++r) {
            const int row = row0 + r;
            const float zpq = p_ftr[row * 3 + 0] * wp0 + p_ftr[row * 3 + 1] * wp1 +
                              p_ftr[row * 3 + 2] * wp2 + q_ftr[row * 3 + 0] * wq0 +
                              q_ftr[row * 3 + 1] * wq1 + q_ftr[row * 3 + 2] * wq2;
            if (mat == 1) Au[row * 256 + j] = acc[r] - zpq;
            else          Av[row * 256 + j] = acc[r] + zpq + lb;
        }
    }
}

// ---- K4: sumAll[j] = sum_m indeg[m] * X[m][j]  (fallback for indeg==0) ----
__global__ __launch_bounds__(256) void k_sumall(const float* __restrict__ X,
                                                const int* __restrict__ indeg,
                                                float* __restrict__ sumAll)
{
    const int j  = threadIdx.x;
    const int m0 = blockIdx.x * 64;        // grid 32
    float s = 0.f;
    for (int m = m0; m < m0 + 64; ++m) {
        s = fmaf((float)indeg[m], X[m * 256 + j], s);
    }
    atomicAdd(&sumAll[j], s);
}

// ---- K5: fixup mv rows for indeg==0 vertices (rare; ~0-2 rows) ----
__global__ __launch_bounds__(256) void k_fix(const int* __restrict__ indeg,
                                             const float* __restrict__ sumAll,
                                             float* __restrict__ out)
{
    const int n = blockIdx.x;              // grid 2048
    if (indeg[n] != 0) return;
    const float v = sumAll[threadIdx.x] * (1.0f / (2.0f * N_E));
    out[n * 256 + threadIdx.x] = (v > 0.f) ? v : expm1f(v);
}

// ---- K6: me_ftr[e'] = leaky(Au[u[e']] + Av[v[e']]) ----
__global__ __launch_bounds__(256) void k_me(const int* __restrict__ src,
                                            const int* __restrict__ dst,
                                            const float* __restrict__ Au,
                                            const float* __restrict__ Av,
                                            float* __restrict__ out_me)
{
    const int t    = threadIdx.x;
    const int lane = t & 63;
    const int e    = blockIdx.x * 4 + (t >> 6);  // 4 edges per block, 1 wave each
    int u, v;
    if (e < N_E) { u = src[e]; v = dst[e]; }
    else         { u = dst[e - N_E]; v = src[e - N_E]; }
    const float4 a = *reinterpret_cast<const float4*>(&Au[u * 256 + lane * 4]);
    const float4 b = *reinterpret_cast<const float4*>(&Av[v * 256 + lane * 4]);
    float4 o;
    o.x = leaky(a.x + b.x);
    o.y = leaky(a.y + b.y);
    o.z = leaky(a.z + b.z);
    o.w = leaky(a.w + b.w);
    *reinterpret_cast<float4*>(&out_me[e * 256 + lane * 4]) = o;
}

extern "C" void kernel_launch(void* const* d_in, const int* in_sizes, int n_in,
                              void* d_out, int out_size, void* d_ws, size_t ws_size,
                              hipStream_t stream) {
    const float* hv       = (const float*)d_in[0];
    // d_in[1] he_ftr: unused (align path is dead code — softmax weights sum to 1)
    const float* p_ftr    = (const float*)d_in[2];
    const float* q_ftr    = (const float*)d_in[3];
    const float* vew1     = (const float*)d_in[4];
    const float* vew2     = (const float*)d_in[5];
    // d_in[6], d_in[7] veb1/veb2: redundant with vew
    const float* attend_w = (const float*)d_in[8];
    const float* attend_b = (const float*)d_in[9];
    // d_in[10], d_in[11] align_w/align_b: dead code
    const float* link_w   = (const float*)d_in[12];
    const float* link_b   = (const float*)d_in[13];

    float* out = (float*)d_out;
    float* ws  = (float*)d_ws;

    int*   src    = (int*)ws;              // [0, 8192)
    int*   dst    = src + N_E;             // [8192, 16384)
    int*   indeg  = dst + N_E;             // [16384, 18432)
    float* sumAll = ws + 18432;            // [18432, 18688)
    float* X      = ws + 32768;
    float* Au     = X + N_V * 256;
    float* Av     = Au + N_V * 256;

    // zero indeg + sumAll in one contiguous memset (ws is poisoned to 0xAA)
    hipMemsetAsync(indeg, 0, (N_V + 256) * sizeof(int), stream);

    k_scan<<<2 * SCAN_BPM, 256, 0, stream>>>((const float4*)vew1,
                                             (const float4*)vew2, src, dst);

    k_indeg<<<N_E / 256, 256, 0, stream>>>(src, dst, indeg);

    dim3 g2(N_V / 8, 3);
    k_gemm<<<g2, 256, 0, stream>>>(hv, attend_w, attend_b, link_w, link_b,
                                   p_ftr, q_ftr, X, Au, Av, out);

    k_sumall<<<32, 256, 0, stream>>>(X, indeg, sumAll);

    k_fix<<<N_V, 256, 0, stream>>>(indeg, sumAll, out);

    k_me<<<(2 * N_E) / 4, 256, 0, stream>>>(src, dst, Au, Av, out + N_V * 256);
}